// Round 1
// baseline (2533.563 us; speedup 1.0000x reference)
//
#include <hip/hip_runtime.h>
#include <stdint.h>
#include <stddef.h>

// Problem constants
#define HD 512      // hidden dim
#define NP 11       // num patches
#define PT 200      // patch size
#define PSTRIDE 180
#define OL 2000     // output length
#define NC 8        // channels
#define NB 1024     // batch
#define M_ROWS (NB*NP*NC)   // 90112 rows for decode GEMMs

typedef __bf16 bf16x8 __attribute__((ext_vector_type(8)));
typedef float floatx4 __attribute__((ext_vector_type(4)));

__device__ __forceinline__ unsigned short f2bf(float f) {
    unsigned int u = __float_as_uint(f);
    u = u + 0x7FFFu + ((u >> 16) & 1u);   // round-to-nearest-even
    return (unsigned short)(u >> 16);
}
__device__ __forceinline__ float bf2f(unsigned short s) {
    return __uint_as_float(((unsigned int)s) << 16);
}
__device__ __forceinline__ float gelu_erf(float x) {
    return 0.5f * x * (1.0f + erff(x * 0.70710678118654752440f));
}

// ---------------- cast X fp32 -> bf16 (46,137,344 elems, exact grid) -------
__global__ __launch_bounds__(256) void cast_x_kernel(const float* __restrict__ x,
                                                     unsigned short* __restrict__ xb) {
    int idx = blockIdx.x * 256 + threadIdx.x;     // float4 index, exact
    float4 v = ((const float4*)x)[idx];
    ushort4 o;
    o.x = f2bf(v.x); o.y = f2bf(v.y); o.z = f2bf(v.z); o.w = f2bf(v.w);
    ((ushort4*)xb)[idx] = o;
}

// ---------------- weight prep: W1 (K,N)->W1t bf16 (N,K); W2 -> W2t padded --
__global__ __launch_bounds__(256) void prep_w_kernel(const float* __restrict__ W1,
                                                     const float* __restrict__ W2,
                                                     unsigned short* __restrict__ W1t,
                                                     unsigned short* __restrict__ W2t) {
    int idx = blockIdx.x * 256 + threadIdx.x;     // 393216 exact
    if (idx < 512 * 512) {
        int n = idx >> 9, k = idx & 511;
        W1t[idx] = f2bf(W1[k * 512 + n]);
    } else {
        int j = idx - 512 * 512;                  // < 256*512
        int n = j >> 9, k = j & 511;
        W2t[j] = (n < PT) ? f2bf(W2[k * PT + n]) : (unsigned short)0;
    }
}

// ---------------- bf16 MFMA GEMM: C = act(A @ Bt^T + bias) -----------------
// A: M x 512 bf16 row-major. Bt: N x 512 bf16 (n-major, k-contiguous).
// Tile 128x128, BK=32, 4 waves in 2x2, each wave 64x64 (4x4 mfma 16x16x32).
template<bool FUSE_GELU, bool OUT_BF16>
__global__ __launch_bounds__(256) void gemm_kernel(const unsigned short* __restrict__ A,
                                                   const unsigned short* __restrict__ Bt,
                                                   const float* __restrict__ bias,
                                                   void* __restrict__ Cout,
                                                   int out_stride, int n_valid) {
    __shared__ __align__(16) unsigned short As[128 * 32];
    __shared__ __align__(16) unsigned short Bs[128 * 32];
    const int tid  = threadIdx.x;
    const int lane = tid & 63;
    const int wid  = tid >> 6;
    const int m0 = blockIdx.x * 128;
    const int n0 = blockIdx.y * 128;
    const int mw = (wid >> 1) * 64;
    const int nw = (wid & 1) * 64;
    const int l15  = lane & 15;
    const int quad = lane >> 4;

    floatx4 acc[4][4];
#pragma unroll
    for (int i = 0; i < 4; ++i)
#pragma unroll
        for (int j = 0; j < 4; ++j) acc[i][j] = (floatx4)0.0f;

    for (int k0 = 0; k0 < 512; k0 += 32) {
        // stage 128x32 bf16 tiles of A and Bt (16B per thread per pass)
#pragma unroll
        for (int p = 0; p < 2; ++p) {
            int ci  = tid + p * 256;     // 0..511
            int row = ci >> 2;           // 0..127
            int c16 = ci & 3;            // 16B chunk within 64B row
            int4 va = *(const int4*)(A  + (size_t)(m0 + row) * 512 + k0 + c16 * 8);
            *(int4*)(As + row * 32 + c16 * 8) = va;
            int4 vb = *(const int4*)(Bt + (size_t)(n0 + row) * 512 + k0 + c16 * 8);
            *(int4*)(Bs + row * 32 + c16 * 8) = vb;
        }
        __syncthreads();
        bf16x8 af[4], bfr[4];
#pragma unroll
        for (int t = 0; t < 4; ++t) {
            af[t]  = *(const bf16x8*)(As + (mw + t * 16 + l15) * 32 + quad * 8);
            bfr[t] = *(const bf16x8*)(Bs + (nw + t * 16 + l15) * 32 + quad * 8);
        }
#pragma unroll
        for (int mt = 0; mt < 4; ++mt)
#pragma unroll
            for (int nt = 0; nt < 4; ++nt)
                acc[mt][nt] = __builtin_amdgcn_mfma_f32_16x16x32_bf16(af[mt], bfr[nt], acc[mt][nt], 0, 0, 0);
        __syncthreads();
    }

    // epilogue: C/D layout col=lane&15, row=quad*4+reg
#pragma unroll
    for (int mt = 0; mt < 4; ++mt) {
#pragma unroll
        for (int nt = 0; nt < 4; ++nt) {
            const int col  = n0 + nw + nt * 16 + l15;
            const int rowb = m0 + mw + mt * 16 + quad * 4;
            const bool colok = (col < n_valid);
            float bv = colok ? bias[col] : 0.0f;
#pragma unroll
            for (int r = 0; r < 4; ++r) {
                float v = acc[mt][nt][r] + bv;
                if (FUSE_GELU) v = gelu_erf(v);
                if (colok) {
                    size_t off = (size_t)(rowb + r) * out_stride + col;
                    if (OUT_BF16) ((unsigned short*)Cout)[off] = f2bf(v);
                    else          ((float*)Cout)[off] = v;
                }
            }
        }
    }
}

// ---------------- overlap-add with triangular fade window ------------------
__global__ __launch_bounds__(256) void oadd_kernel(const float* __restrict__ patches,
                                                   float* __restrict__ rec) {
    int idx = blockIdx.x * 256 + threadIdx.x;   // exact 16,384,000
    int l  = idx % OL;
    int bc = idx / OL;       // b*8+c
    int c  = bc & 7;
    int b  = bc >> 3;
    int imin = (l >= PT) ? (l - (PT - PSTRIDE)) / PSTRIDE : 0;   // ceil((l-199)/180)
    int imax = l / PSTRIDE; if (imax > NP - 1) imax = NP - 1;
    float acc = 0.0f, wsum = 0.0f;
    for (int i = imin; i <= imax; ++i) {
        int t = l - i * PSTRIDE;
        float w = (t < 50) ? t * (1.0f / 49.0f)
                           : ((t >= 150) ? (199 - t) * (1.0f / 49.0f) : 1.0f);
        acc  += patches[(((size_t)b * NP + i) * NC + c) * PT + t] * w;
        wsum += w;
    }
    rec[idx] = acc / fmaxf(wsum, 1e-8f);
}

// ---------------- conv1: rec(8ch) -> gelu -> c1(32ch) bf16, k=15 p=7 -------
__global__ __launch_bounds__(256) void conv1_kernel(const float* __restrict__ rec,
                                                    const float* __restrict__ rw1,
                                                    const float* __restrict__ rb1,
                                                    unsigned short* __restrict__ c1) {
    __shared__ float rs[8][272];    // 270 used (256 + 14 halo)
    __shared__ float ws[3840];
    __shared__ float bs[32];
    const int tid  = threadIdx.x;
    const int b    = blockIdx.y;
    const int seg0 = blockIdx.x * 256;
    for (int i = tid; i < 3840; i += 256) ws[i] = rw1[i];
    if (tid < 32) bs[tid] = rb1[tid];
    for (int i = tid; i < 8 * 270; i += 256) {
        int ic = i / 270, j = i % 270;
        int l = seg0 - 7 + j;
        rs[ic][j] = (l >= 0 && l < OL) ? rec[((size_t)b * 8 + ic) * OL + l] : 0.0f;
    }
    __syncthreads();
    const int pos0 = (tid & 63) * 4;
    const int l0   = seg0 + pos0;
    if (l0 >= OL) return;
#pragma unroll
    for (int p = 0; p < 8; ++p) {
        const int oc = (tid >> 6) + 4 * p;
        float a0 = bs[oc], a1 = a0, a2 = a0, a3 = a0;
#pragma unroll
        for (int ic = 0; ic < 8; ++ic) {
            float x[20];
            *(float4*)&x[0]  = *(const float4*)&rs[ic][pos0];
            *(float4*)&x[4]  = *(const float4*)&rs[ic][pos0 + 4];
            *(float4*)&x[8]  = *(const float4*)&rs[ic][pos0 + 8];
            *(float4*)&x[12] = *(const float4*)&rs[ic][pos0 + 12];
            *(float4*)&x[16] = *(const float4*)&rs[ic][pos0 + 16];
            const float* wr = &ws[(oc * 8 + ic) * 15];
#pragma unroll
            for (int k = 0; k < 15; ++k) {
                float w = wr[k];
                a0 += w * x[k]; a1 += w * x[k + 1]; a2 += w * x[k + 2]; a3 += w * x[k + 3];
            }
        }
        ushort4 o;
        o.x = f2bf(gelu_erf(a0)); o.y = f2bf(gelu_erf(a1));
        o.z = f2bf(gelu_erf(a2)); o.w = f2bf(gelu_erf(a3));
        *(ushort4*)(c1 + ((size_t)b * 32 + oc) * OL + l0) = o;
    }
}

// ---------------- conv2: c1(32ch bf16) -> gelu -> c2(16ch) bf16 ------------
__global__ __launch_bounds__(256) void conv2_kernel(const unsigned short* __restrict__ c1,
                                                    const float* __restrict__ rw2,
                                                    const float* __restrict__ rb2,
                                                    unsigned short* __restrict__ c2) {
    __shared__ float xs[32][272];   // 34816 B
    __shared__ float ws[7680];      // 30720 B  (total 65536 = exactly 64KB)
    const int tid  = threadIdx.x;
    const int b    = blockIdx.y;
    const int seg0 = blockIdx.x * 256;
    for (int i = tid; i < 7680; i += 256) ws[i] = rw2[i];
    for (int i = tid; i < 32 * 270; i += 256) {
        int ic = i / 270, j = i % 270;
        int l = seg0 - 7 + j;
        xs[ic][j] = (l >= 0 && l < OL) ? bf2f(c1[((size_t)b * 32 + ic) * OL + l]) : 0.0f;
    }
    __syncthreads();
    const int pos0 = (tid & 63) * 4;
    const int l0   = seg0 + pos0;
    if (l0 >= OL) return;
#pragma unroll
    for (int p = 0; p < 4; ++p) {
        const int oc = (tid >> 6) + 4 * p;
        float bias = rb2[oc];
        float a0 = bias, a1 = bias, a2 = bias, a3 = bias;
        for (int ic = 0; ic < 32; ++ic) {
            float x[20];
            *(float4*)&x[0]  = *(const float4*)&xs[ic][pos0];
            *(float4*)&x[4]  = *(const float4*)&xs[ic][pos0 + 4];
            *(float4*)&x[8]  = *(const float4*)&xs[ic][pos0 + 8];
            *(float4*)&x[12] = *(const float4*)&xs[ic][pos0 + 12];
            *(float4*)&x[16] = *(const float4*)&xs[ic][pos0 + 16];
            const float* wr = &ws[(oc * 32 + ic) * 15];
#pragma unroll
            for (int k = 0; k < 15; ++k) {
                float w = wr[k];
                a0 += w * x[k]; a1 += w * x[k + 1]; a2 += w * x[k + 2]; a3 += w * x[k + 3];
            }
        }
        ushort4 o;
        o.x = f2bf(gelu_erf(a0)); o.y = f2bf(gelu_erf(a1));
        o.z = f2bf(gelu_erf(a2)); o.w = f2bf(gelu_erf(a3));
        *(ushort4*)(c2 + ((size_t)b * 16 + oc) * OL + l0) = o;
    }
}

// ---------------- conv3 + residual + pointwise proj -> d_out ---------------
__global__ __launch_bounds__(256) void conv3pw_kernel(const unsigned short* __restrict__ c2,
                                                      const float* __restrict__ rec,
                                                      const float* __restrict__ rw3,
                                                      const float* __restrict__ rb3,
                                                      const float* __restrict__ pw,
                                                      const float* __restrict__ pb,
                                                      float* __restrict__ out) {
    __shared__ float xs[16][272];   // c2 tile (270 used)
    __shared__ float r2[8][256];    // rec + conv3 result
    __shared__ float ws[1920];
    __shared__ float pws[64];
    __shared__ float bs3[8], bsp[8];
    const int tid  = threadIdx.x;
    const int b    = blockIdx.y;
    const int seg0 = blockIdx.x * 256;
    for (int i = tid; i < 1920; i += 256) ws[i] = rw3[i];
    if (tid < 64) pws[tid] = pw[tid];
    if (tid < 8)  bs3[tid] = rb3[tid];
    if (tid >= 8 && tid < 16) bsp[tid - 8] = pb[tid - 8];
    for (int i = tid; i < 16 * 270; i += 256) {
        int ic = i / 270, j = i % 270;
        int l = seg0 - 7 + j;
        xs[ic][j] = (l >= 0 && l < OL) ? bf2f(c2[((size_t)b * 16 + ic) * OL + l]) : 0.0f;
    }
    for (int i = tid; i < 8 * 256; i += 256) {
        int c = i / 256, j = i % 256;
        int l = seg0 + j;
        r2[c][j] = (l < OL) ? rec[((size_t)b * 8 + c) * OL + l] : 0.0f;
    }
    __syncthreads();
    const int pos0 = (tid & 63) * 4;
    const int l0   = seg0 + pos0;
    const bool ok  = (l0 < OL);
#pragma unroll
    for (int p = 0; p < 2; ++p) {
        const int oc = (tid >> 6) + 4 * p;
        if (ok) {
            float a0 = bs3[oc], a1 = a0, a2 = a0, a3 = a0;
#pragma unroll
            for (int ic = 0; ic < 16; ++ic) {
                float x[20];
                *(float4*)&x[0]  = *(const float4*)&xs[ic][pos0];
                *(float4*)&x[4]  = *(const float4*)&xs[ic][pos0 + 4];
                *(float4*)&x[8]  = *(const float4*)&xs[ic][pos0 + 8];
                *(float4*)&x[12] = *(const float4*)&xs[ic][pos0 + 12];
                *(float4*)&x[16] = *(const float4*)&xs[ic][pos0 + 16];
                const float* wr = &ws[(oc * 16 + ic) * 15];
#pragma unroll
                for (int k = 0; k < 15; ++k) {
                    float w = wr[k];
                    a0 += w * x[k]; a1 += w * x[k + 1]; a2 += w * x[k + 2]; a3 += w * x[k + 3];
                }
            }
            r2[oc][pos0]     += a0;
            r2[oc][pos0 + 1] += a1;
            r2[oc][pos0 + 2] += a2;
            r2[oc][pos0 + 3] += a3;
        }
    }
    __syncthreads();
#pragma unroll
    for (int p = 0; p < 2; ++p) {
        const int o = (tid >> 6) + 4 * p;
        if (ok) {
            float4 v;
            v.x = bsp[o]; v.y = bsp[o]; v.z = bsp[o]; v.w = bsp[o];
#pragma unroll
            for (int c = 0; c < 8; ++c) {
                float w = pws[o * 8 + c];
                float4 rv = *(const float4*)&r2[c][pos0];
                v.x += w * rv.x; v.y += w * rv.y; v.z += w * rv.z; v.w += w * rv.w;
            }
            *(float4*)(out + ((size_t)b * 8 + o) * OL + l0) = v;
        }
    }
}

// ---------------------------------------------------------------------------
extern "C" void kernel_launch(void* const* d_in, const int* in_sizes, int n_in,
                              void* d_out, int out_size, void* d_ws, size_t ws_size,
                              hipStream_t stream) {
    const float* X   = (const float*)d_in[0];
    const float* W1  = (const float*)d_in[1];
    const float* b1  = (const float*)d_in[2];
    const float* W2  = (const float*)d_in[3];
    const float* b2  = (const float*)d_in[4];
    const float* rw1 = (const float*)d_in[5];
    const float* rb1 = (const float*)d_in[6];
    const float* rw2 = (const float*)d_in[7];
    const float* rb2 = (const float*)d_in[8];
    const float* rw3 = (const float*)d_in[9];
    const float* rb3 = (const float*)d_in[10];
    const float* pw  = (const float*)d_in[11];
    const float* pb  = (const float*)d_in[12];
    float* out = (float*)d_out;

    // workspace layout (bytes); c1/c2 alias regions dead after overlap-add
    char* ws = (char*)d_ws;
    unsigned short* Xb   = (unsigned short*)(ws);               //  92,274,688
    unsigned short* W1t  = (unsigned short*)(ws +  92274688);   //     524,288
    unsigned short* W2t  = (unsigned short*)(ws +  92798976);   //     262,144
    unsigned short* h    = (unsigned short*)(ws +  93061120);   //  92,274,688
    float*          pat  = (float*)         (ws + 185335808);   //  72,089,600
    float*          rec  = (float*)         (ws + 257425408);   //  65,536,000 -> total 322,961,408
    unsigned short* c1   = (unsigned short*)(ws);               // 131,072,000 (over dead Xb/W/h-head)
    unsigned short* c2   = (unsigned short*)(ws + 131072000);   //  65,536,000 (over dead h-tail/pat-head)

    cast_x_kernel<<<45056, 256, 0, stream>>>(X, Xb);
    prep_w_kernel<<<1536, 256, 0, stream>>>(W1, W2, W1t, W2t);
    gemm_kernel<true,  true ><<<dim3(704, 4), 256, 0, stream>>>(Xb, W1t, b1, (void*)h,   512, 512);
    gemm_kernel<false, false><<<dim3(704, 2), 256, 0, stream>>>(h,  W2t, b2, (void*)pat, 200, 200);
    oadd_kernel<<<64000, 256, 0, stream>>>(pat, rec);
    conv1_kernel<<<dim3(8, 1024), 256, 0, stream>>>(rec, rw1, rb1, c1);
    conv2_kernel<<<dim3(8, 1024), 256, 0, stream>>>(c1, rw2, rb2, c2);
    conv3pw_kernel<<<dim3(8, 1024), 256, 0, stream>>>(c2, rec, rw3, rb3, pw, pb, out);
}

// Round 2
// 651.445 us; speedup vs baseline: 3.8891x; 3.8891x over previous
//
#include <hip/hip_runtime.h>
#include <stdint.h>
#include <stddef.h>

#define HD 512
#define NP 11
#define PT 200
#define PSTRIDE 180
#define OL 2000
#define NC 8
#define NB 1024

typedef __bf16 bf16x8 __attribute__((ext_vector_type(8)));
typedef float floatx4 __attribute__((ext_vector_type(4)));

__device__ __forceinline__ unsigned short f2bf(float f) {
    unsigned int u = __float_as_uint(f);
    u = u + 0x7FFFu + ((u >> 16) & 1u);
    return (unsigned short)(u >> 16);
}
__device__ __forceinline__ float gelu_erf(float x) {
    return 0.5f * x * (1.0f + erff(x * 0.70710678118654752440f));
}

// ---------------- cast X fp32 -> bf16 ------------------------------------
__global__ __launch_bounds__(256) void cast_x_kernel(const float* __restrict__ x,
                                                     unsigned short* __restrict__ xb) {
    int idx = blockIdx.x * 256 + threadIdx.x;
    float4 v = ((const float4*)x)[idx];
    ushort4 o;
    o.x = f2bf(v.x); o.y = f2bf(v.y); o.z = f2bf(v.z); o.w = f2bf(v.w);
    ((ushort4*)xb)[idx] = o;
}

// ---------------- GEMM weight prep ---------------------------------------
__global__ __launch_bounds__(256) void prep_w_kernel(const float* __restrict__ W1,
                                                     const float* __restrict__ W2,
                                                     unsigned short* __restrict__ W1t,
                                                     unsigned short* __restrict__ W2t) {
    int idx = blockIdx.x * 256 + threadIdx.x;
    if (idx < 512 * 512) {
        int n = idx >> 9, k = idx & 511;
        W1t[idx] = f2bf(W1[k * 512 + n]);
    } else {
        int j = idx - 512 * 512;
        int n = j >> 9, k = j & 511;
        W2t[j] = (n < PT) ? f2bf(W2[k * PT + n]) : (unsigned short)0;
    }
}

// ---------------- conv weight prep: A-fragment order, bf16 ---------------
// Wt1[kb4][oc32][k32], k=tl*8+ic, tap=kb*4+tl (taps 15 padded to 16 w/ 0)
// Wt2[t15][oc16][ic32]
// Wt3[kb8][m16][k32], k=tl*16+ic, tap=kb*2+tl, rows m>=8 zero
__global__ __launch_bounds__(256) void prep_cw_kernel(const float* __restrict__ rw1,
                                                      const float* __restrict__ rw2,
                                                      const float* __restrict__ rw3,
                                                      unsigned short* __restrict__ Wt1,
                                                      unsigned short* __restrict__ Wt2,
                                                      unsigned short* __restrict__ Wt3) {
    int idx = blockIdx.x * 256 + threadIdx.x;   // 15872 exact (62 blocks)
    if (idx < 4096) {
        int kb = idx >> 10, rem = idx & 1023, oc = rem >> 5, k = rem & 31;
        int tl = k >> 3, ic = k & 7, tap = kb * 4 + tl;
        Wt1[idx] = (tap < 15) ? f2bf(rw1[(oc * 8 + ic) * 15 + tap]) : (unsigned short)0;
    } else if (idx < 4096 + 7680) {
        int j = idx - 4096;
        int t = j >> 9, rem = j & 511, oc = rem >> 5, ic = rem & 31;
        Wt2[j] = f2bf(rw2[(oc * 32 + ic) * 15 + t]);
    } else {
        int j = idx - 11776;   // < 4096
        int kb = j >> 9, rem = j & 511, m = rem >> 5, k = rem & 31;
        int tl = k >> 4, ic = k & 15, tap = kb * 2 + tl;
        Wt3[j] = (m < 8 && tap < 15) ? f2bf(rw3[(m * 16 + ic) * 15 + tap]) : (unsigned short)0;
    }
}

// ---------------- bf16 MFMA GEMM (unchanged from R0, passes) --------------
template<bool FUSE_GELU, bool OUT_BF16>
__global__ __launch_bounds__(256) void gemm_kernel(const unsigned short* __restrict__ A,
                                                   const unsigned short* __restrict__ Bt,
                                                   const float* __restrict__ bias,
                                                   void* __restrict__ Cout,
                                                   int out_stride, int n_valid) {
    __shared__ __align__(16) unsigned short As[128 * 32];
    __shared__ __align__(16) unsigned short Bs[128 * 32];
    const int tid  = threadIdx.x;
    const int lane = tid & 63;
    const int wid  = tid >> 6;
    const int m0 = blockIdx.x * 128;
    const int n0 = blockIdx.y * 128;
    const int mw = (wid >> 1) * 64;
    const int nw = (wid & 1) * 64;
    const int l15  = lane & 15;
    const int quad = lane >> 4;

    floatx4 acc[4][4];
#pragma unroll
    for (int i = 0; i < 4; ++i)
#pragma unroll
        for (int j = 0; j < 4; ++j) acc[i][j] = (floatx4)0.0f;

    for (int k0 = 0; k0 < 512; k0 += 32) {
#pragma unroll
        for (int p = 0; p < 2; ++p) {
            int ci  = tid + p * 256;
            int row = ci >> 2;
            int c16 = ci & 3;
            int4 va = *(const int4*)(A  + (size_t)(m0 + row) * 512 + k0 + c16 * 8);
            *(int4*)(As + row * 32 + c16 * 8) = va;
            int4 vb = *(const int4*)(Bt + (size_t)(n0 + row) * 512 + k0 + c16 * 8);
            *(int4*)(Bs + row * 32 + c16 * 8) = vb;
        }
        __syncthreads();
        bf16x8 af[4], bfr[4];
#pragma unroll
        for (int t = 0; t < 4; ++t) {
            af[t]  = *(const bf16x8*)(As + (mw + t * 16 + l15) * 32 + quad * 8);
            bfr[t] = *(const bf16x8*)(Bs + (nw + t * 16 + l15) * 32 + quad * 8);
        }
#pragma unroll
        for (int mt = 0; mt < 4; ++mt)
#pragma unroll
            for (int nt = 0; nt < 4; ++nt)
                acc[mt][nt] = __builtin_amdgcn_mfma_f32_16x16x32_bf16(af[mt], bfr[nt], acc[mt][nt], 0, 0, 0);
        __syncthreads();
    }

#pragma unroll
    for (int mt = 0; mt < 4; ++mt) {
#pragma unroll
        for (int nt = 0; nt < 4; ++nt) {
            const int col  = n0 + nw + nt * 16 + l15;
            const int rowb = m0 + mw + mt * 16 + quad * 4;
            const bool colok = (col < n_valid);
            float bv = colok ? bias[col] : 0.0f;
#pragma unroll
            for (int r = 0; r < 4; ++r) {
                float v = acc[mt][nt][r] + bv;
                if (FUSE_GELU) v = gelu_erf(v);
                if (colok) {
                    size_t off = (size_t)(rowb + r) * out_stride + col;
                    if (OUT_BF16) ((unsigned short*)Cout)[off] = f2bf(v);
                    else          ((float*)Cout)[off] = v;
                }
            }
        }
    }
}

// ---------------- overlap-add -> rec in pos-major [B][2000][8] fp32 -------
__global__ __launch_bounds__(256) void oadd_kernel(const float* __restrict__ patches,
                                                   float* __restrict__ rec) {
    int idx = blockIdx.x * 256 + threadIdx.x;   // exact 2,048,000
    int l = idx % OL;
    int b = idx / OL;
    int imin = (l >= PT) ? (l - (PT - PSTRIDE)) / PSTRIDE : 0;
    int imax = l / PSTRIDE; if (imax > NP - 1) imax = NP - 1;
    float acc[8];
#pragma unroll
    for (int c = 0; c < 8; ++c) acc[c] = 0.0f;
    float wsum = 0.0f;
    for (int i = imin; i <= imax; ++i) {
        int t = l - i * PSTRIDE;
        float w = (t < 50) ? t * (1.0f / 49.0f)
                           : ((t >= 150) ? (199 - t) * (1.0f / 49.0f) : 1.0f);
        wsum += w;
        const float* p = patches + ((size_t)(b * NP + i) * NC) * PT + t;
#pragma unroll
        for (int c = 0; c < 8; ++c) acc[c] += p[c * PT] * w;
    }
    float inv = 1.0f / fmaxf(wsum, 1e-8f);
    float4 v0 = { acc[0] * inv, acc[1] * inv, acc[2] * inv, acc[3] * inv };
    float4 v1 = { acc[4] * inv, acc[5] * inv, acc[6] * inv, acc[7] * inv };
    float* o = rec + (size_t)idx * 8;
    *(float4*)o = v0;
    *(float4*)(o + 4) = v1;
}

// ---------------- conv1 (8->32, k15) via MFMA -----------------------------
// rec pos-major fp32 -> c1 pos-major bf16 [B][2000][32]
__global__ __launch_bounds__(256) void conv1_mfma(const float* __restrict__ rec,
                                                  const unsigned short* __restrict__ Wt1,
                                                  const float* __restrict__ rb1,
                                                  unsigned short* __restrict__ c1) {
    __shared__ __align__(16) unsigned short xs[272 * 8];    // [row][8ic], row=pos+7
    __shared__ __align__(16) unsigned short ys[256 * 40];   // [pos][32oc], stride 40
    __shared__ float bs[32];
    const int tid = threadIdx.x;
    const int b = blockIdx.y;
    const int seg0 = blockIdx.x * 256;
    const int lane = tid & 63, wid = tid >> 6;
    const int l15 = lane & 15, quad = lane >> 4;

    if (tid < 32) bs[tid] = rb1[tid];
    for (int i = tid; i < 544; i += 256) {
        int row = i >> 1, half = i & 1;
        int p = seg0 - 7 + row;
        float4 v = (p >= 0 && p < OL) ? *(const float4*)(rec + ((size_t)b * OL + p) * 8 + half * 4)
                                      : make_float4(0.f, 0.f, 0.f, 0.f);
        ushort4 o; o.x = f2bf(v.x); o.y = f2bf(v.y); o.z = f2bf(v.z); o.w = f2bf(v.w);
        *(ushort4*)(xs + row * 8 + half * 4) = o;
    }
    bf16x8 wfrag[4][2];
#pragma unroll
    for (int kb = 0; kb < 4; ++kb)
#pragma unroll
        for (int ot = 0; ot < 2; ++ot)
            wfrag[kb][ot] = *(const bf16x8*)(Wt1 + (kb * 32 + ot * 16 + l15) * 32 + quad * 8);
    __syncthreads();

    floatx4 acc[2][4];
#pragma unroll
    for (int ot = 0; ot < 2; ++ot)
#pragma unroll
        for (int u = 0; u < 4; ++u) acc[ot][u] = (floatx4)0.0f;

#pragma unroll
    for (int u = 0; u < 4; ++u) {
        const int posl = wid * 64 + u * 16 + l15;
#pragma unroll
        for (int kb = 0; kb < 4; ++kb) {
            int row = posl + kb * 4 + quad;   // tap = kb*4+quad
            bf16x8 bfrag = *(const bf16x8*)(xs + row * 8);
#pragma unroll
            for (int ot = 0; ot < 2; ++ot)
                acc[ot][u] = __builtin_amdgcn_mfma_f32_16x16x32_bf16(wfrag[kb][ot], bfrag, acc[ot][u], 0, 0, 0);
        }
    }
#pragma unroll
    for (int ot = 0; ot < 2; ++ot)
#pragma unroll
        for (int u = 0; u < 4; ++u) {
            int posl = wid * 64 + u * 16 + l15;
#pragma unroll
            for (int r = 0; r < 4; ++r) {
                int oc = ot * 16 + quad * 4 + r;
                ys[posl * 40 + oc] = f2bf(gelu_erf(acc[ot][u][r] + bs[oc]));
            }
        }
    __syncthreads();
    for (int i = tid; i < 1024; i += 256) {
        int row = i >> 2, ch = i & 3;
        int p = seg0 + row;
        if (p < OL)
            *(int4*)(c1 + ((size_t)b * OL + p) * 32 + ch * 8) = *(const int4*)(ys + row * 40 + ch * 8);
    }
}

// ---------------- conv2 (32->16, k15) via MFMA ----------------------------
__global__ __launch_bounds__(256) void conv2_mfma(const unsigned short* __restrict__ c1,
                                                  const unsigned short* __restrict__ Wt2,
                                                  const float* __restrict__ rb2,
                                                  unsigned short* __restrict__ c2) {
    __shared__ __align__(16) unsigned short xs[270 * 40];   // [row][32ic], stride 40
    __shared__ __align__(16) unsigned short ys[256 * 24];   // [pos][16oc], stride 24
    __shared__ float bs[16];
    const int tid = threadIdx.x;
    const int b = blockIdx.y;
    const int seg0 = blockIdx.x * 256;
    const int lane = tid & 63, wid = tid >> 6;
    const int l15 = lane & 15, quad = lane >> 4;

    if (tid < 16) bs[tid] = rb2[tid];
    for (int i = tid; i < 1080; i += 256) {
        int row = i >> 2, ch = i & 3;
        int p = seg0 - 7 + row;
        int4 v = (p >= 0 && p < OL) ? *(const int4*)(c1 + ((size_t)b * OL + p) * 32 + ch * 8)
                                    : make_int4(0, 0, 0, 0);
        *(int4*)(xs + row * 40 + ch * 8) = v;
    }
    bf16x8 wfrag[15];
#pragma unroll
    for (int t = 0; t < 15; ++t)
        wfrag[t] = *(const bf16x8*)(Wt2 + (t * 16 + l15) * 32 + quad * 8);
    __syncthreads();

    floatx4 acc[4];
#pragma unroll
    for (int u = 0; u < 4; ++u) acc[u] = (floatx4)0.0f;

#pragma unroll
    for (int u = 0; u < 4; ++u) {
        const int posl = wid * 64 + u * 16 + l15;
#pragma unroll
        for (int t = 0; t < 15; ++t) {
            bf16x8 bfrag = *(const bf16x8*)(xs + (posl + t) * 40 + quad * 8);
            acc[u] = __builtin_amdgcn_mfma_f32_16x16x32_bf16(wfrag[t], bfrag, acc[u], 0, 0, 0);
        }
    }
#pragma unroll
    for (int u = 0; u < 4; ++u) {
        int posl = wid * 64 + u * 16 + l15;
#pragma unroll
        for (int r = 0; r < 4; ++r) {
            int oc = quad * 4 + r;
            ys[posl * 24 + oc] = f2bf(gelu_erf(acc[u][r] + bs[oc]));
        }
    }
    __syncthreads();
    for (int i = tid; i < 512; i += 256) {
        int row = i >> 1, ch = i & 1;
        int p = seg0 + row;
        if (p < OL)
            *(int4*)(c2 + ((size_t)b * OL + p) * 16 + ch * 8) = *(const int4*)(ys + row * 24 + ch * 8);
    }
}

// ---------------- conv3 (16->8) + residual + pointwise -> out -------------
__global__ __launch_bounds__(256) void conv3pw_mfma(const unsigned short* __restrict__ c2,
                                                    const float* __restrict__ rec,
                                                    const unsigned short* __restrict__ Wt3,
                                                    const float* __restrict__ rb3,
                                                    const float* __restrict__ pw,
                                                    const float* __restrict__ pb,
                                                    float* __restrict__ out) {
    __shared__ __align__(16) unsigned short xs[272 * 24];   // [row][16ic], stride 24
    __shared__ __align__(16) float r2[256 * 12];            // [pos][8c], stride 12
    __shared__ float pws[64], bs3[8], bsp[8];
    const int tid = threadIdx.x;
    const int b = blockIdx.y;
    const int seg0 = blockIdx.x * 256;
    const int lane = tid & 63, wid = tid >> 6;
    const int l15 = lane & 15, quad = lane >> 4;

    if (tid < 64) pws[tid] = pw[tid];
    if (tid >= 64 && tid < 72) bs3[tid - 64] = rb3[tid - 64];
    if (tid >= 72 && tid < 80) bsp[tid - 72] = pb[tid - 72];
    for (int i = tid; i < 544; i += 256) {
        int row = i >> 1, ch = i & 1;
        int p = seg0 - 7 + row;
        int4 v = (p >= 0 && p < OL) ? *(const int4*)(c2 + ((size_t)b * OL + p) * 16 + ch * 8)
                                    : make_int4(0, 0, 0, 0);
        *(int4*)(xs + row * 24 + ch * 8) = v;
    }
    for (int i = tid; i < 512; i += 256) {
        int row = i >> 1, half = i & 1;
        int p = seg0 + row;
        float4 v = (p < OL) ? *(const float4*)(rec + ((size_t)b * OL + p) * 8 + half * 4)
                            : make_float4(0.f, 0.f, 0.f, 0.f);
        *(float4*)(r2 + row * 12 + half * 4) = v;
    }
    bf16x8 wfrag[8];
#pragma unroll
    for (int kb = 0; kb < 8; ++kb)
        wfrag[kb] = *(const bf16x8*)(Wt3 + (kb * 16 + l15) * 32 + quad * 8);
    __syncthreads();

    floatx4 acc[4];
#pragma unroll
    for (int u = 0; u < 4; ++u) acc[u] = (floatx4)0.0f;

#pragma unroll
    for (int u = 0; u < 4; ++u) {
        const int posl = wid * 64 + u * 16 + l15;
#pragma unroll
        for (int kb = 0; kb < 8; ++kb) {
            int row = posl + kb * 2 + (quad >> 1);   // tap = kb*2 + (quad>>1)
            bf16x8 bfrag = *(const bf16x8*)(xs + row * 24 + (quad & 1) * 8);
            acc[u] = __builtin_amdgcn_mfma_f32_16x16x32_bf16(wfrag[kb], bfrag, acc[u], 0, 0, 0);
        }
    }
    if (quad < 2) {
#pragma unroll
        for (int u = 0; u < 4; ++u) {
            int posl = wid * 64 + u * 16 + l15;
#pragma unroll
            for (int r = 0; r < 4; ++r) {
                int oc = quad * 4 + r;
                r2[posl * 12 + oc] += acc[u][r] + bs3[oc];
            }
        }
    }
    __syncthreads();
    {
        int p = seg0 + tid;
        if (p < OL) {
            float4 a = *(const float4*)(r2 + tid * 12);
            float4 c = *(const float4*)(r2 + tid * 12 + 4);
#pragma unroll
            for (int o = 0; o < 8; ++o) {
                float v = bsp[o];
                v += pws[o * 8 + 0] * a.x + pws[o * 8 + 1] * a.y + pws[o * 8 + 2] * a.z + pws[o * 8 + 3] * a.w;
                v += pws[o * 8 + 4] * c.x + pws[o * 8 + 5] * c.y + pws[o * 8 + 6] * c.z + pws[o * 8 + 7] * c.w;
                out[((size_t)b * 8 + o) * OL + p] = v;
            }
        }
    }
}

// ---------------------------------------------------------------------------
extern "C" void kernel_launch(void* const* d_in, const int* in_sizes, int n_in,
                              void* d_out, int out_size, void* d_ws, size_t ws_size,
                              hipStream_t stream) {
    const float* X   = (const float*)d_in[0];
    const float* W1  = (const float*)d_in[1];
    const float* b1  = (const float*)d_in[2];
    const float* W2  = (const float*)d_in[3];
    const float* b2  = (const float*)d_in[4];
    const float* rw1 = (const float*)d_in[5];
    const float* rb1 = (const float*)d_in[6];
    const float* rw2 = (const float*)d_in[7];
    const float* rb2 = (const float*)d_in[8];
    const float* rw3 = (const float*)d_in[9];
    const float* rb3 = (const float*)d_in[10];
    const float* pw  = (const float*)d_in[11];
    const float* pb  = (const float*)d_in[12];
    float* out = (float*)d_out;

    char* ws = (char*)d_ws;
    unsigned short* Xb  = (unsigned short*)(ws);               //  92,274,688
    unsigned short* W1t = (unsigned short*)(ws +  92274688);   //     524,288
    unsigned short* W2t = (unsigned short*)(ws +  92798976);   //     262,144
    unsigned short* h   = (unsigned short*)(ws +  93061120);   //  92,274,688
    float*          pat = (float*)         (ws + 185335808);   //  72,089,600
    float*          rec = (float*)         (ws + 257425408);   //  65,536,000 (pos-major)
    unsigned short* Wt1 = (unsigned short*)(ws + 322961408);   //       8,192
    unsigned short* Wt2 = (unsigned short*)(ws + 322969600);   //      15,360
    unsigned short* Wt3 = (unsigned short*)(ws + 322984960);   //       8,192 -> 322,993,152 total
    unsigned short* c1  = (unsigned short*)(ws);               // 131,072,000 (over dead Xb/W1t/W2t/h-head)
    unsigned short* c2  = (unsigned short*)(ws + 131072000);   //  65,536,000 (over dead h-tail/pat-head)

    cast_x_kernel<<<45056, 256, 0, stream>>>(X, Xb);
    prep_w_kernel<<<1536, 256, 0, stream>>>(W1, W2, W1t, W2t);
    prep_cw_kernel<<<62, 256, 0, stream>>>(rw1, rw2, rw3, Wt1, Wt2, Wt3);
    gemm_kernel<true,  true ><<<dim3(704, 4), 256, 0, stream>>>(Xb, W1t, b1, (void*)h,   512, 512);
    gemm_kernel<false, false><<<dim3(704, 2), 256, 0, stream>>>(h,  W2t, b2, (void*)pat, 200, 200);
    oadd_kernel<<<8000, 256, 0, stream>>>(pat, rec);
    conv1_mfma<<<dim3(8, NB), 256, 0, stream>>>(rec, Wt1, rb1, c1);
    conv2_mfma<<<dim3(8, NB), 256, 0, stream>>>(c1, Wt2, rb2, c2);
    conv3pw_mfma<<<dim3(8, NB), 256, 0, stream>>>(c2, rec, Wt3, rb3, pw, pb, out);
}

// Round 3
// 602.590 us; speedup vs baseline: 4.2045x; 1.0811x over previous
//
#include <hip/hip_runtime.h>
#include <stdint.h>
#include <stddef.h>

#define HD 512
#define NP 11
#define PT 200
#define PSTRIDE 180
#define OL 2000
#define NC 8
#define NB 1024

typedef __bf16 bf16x8 __attribute__((ext_vector_type(8)));
typedef float floatx4 __attribute__((ext_vector_type(4)));

__device__ __forceinline__ unsigned short f2bf(float f) {
    unsigned int u = __float_as_uint(f);
    u = u + 0x7FFFu + ((u >> 16) & 1u);
    return (unsigned short)(u >> 16);
}
__device__ __forceinline__ float bf2f(unsigned short s) {
    return __uint_as_float(((unsigned int)s) << 16);
}
__device__ __forceinline__ float gelu_erf(float x) {
    return 0.5f * x * (1.0f + erff(x * 0.70710678118654752440f));
}
// async global->LDS, 16B per lane; lptr must be wave-uniform (HW: base + lane*16)
__device__ __forceinline__ void async16(const unsigned short* g, unsigned short* l) {
    __builtin_amdgcn_global_load_lds(
        (const __attribute__((address_space(1))) unsigned int*)g,
        (__attribute__((address_space(3))) unsigned int*)l, 16, 0, 0);
}

// ---------------- cast X fp32 -> bf16 ------------------------------------
__global__ __launch_bounds__(256) void cast_x_kernel(const float* __restrict__ x,
                                                     unsigned short* __restrict__ xb) {
    int idx = blockIdx.x * 256 + threadIdx.x;
    float4 v = ((const float4*)x)[idx];
    ushort4 o;
    o.x = f2bf(v.x); o.y = f2bf(v.y); o.z = f2bf(v.z); o.w = f2bf(v.w);
    ((ushort4*)xb)[idx] = o;
}

// ---------------- GEMM weight prep ---------------------------------------
__global__ __launch_bounds__(256) void prep_w_kernel(const float* __restrict__ W1,
                                                     const float* __restrict__ W2,
                                                     unsigned short* __restrict__ W1t,
                                                     unsigned short* __restrict__ W2t) {
    int idx = blockIdx.x * 256 + threadIdx.x;
    if (idx < 512 * 512) {
        int n = idx >> 9, k = idx & 511;
        W1t[idx] = f2bf(W1[k * 512 + n]);
    } else {
        int j = idx - 512 * 512;
        int n = j >> 9, k = j & 511;
        W2t[j] = (n < PT) ? f2bf(W2[k * PT + n]) : (unsigned short)0;
    }
}

// ---------------- conv weight prep (A-fragment order, bf16) ---------------
__global__ __launch_bounds__(256) void prep_cw_kernel(const float* __restrict__ rw1,
                                                      const float* __restrict__ rw2,
                                                      const float* __restrict__ rw3,
                                                      unsigned short* __restrict__ Wt1,
                                                      unsigned short* __restrict__ Wt2,
                                                      unsigned short* __restrict__ Wt3) {
    int idx = blockIdx.x * 256 + threadIdx.x;   // 15872 exact (62 blocks)
    if (idx < 4096) {
        int kb = idx >> 10, rem = idx & 1023, oc = rem >> 5, k = rem & 31;
        int tl = k >> 3, ic = k & 7, tap = kb * 4 + tl;
        Wt1[idx] = (tap < 15) ? f2bf(rw1[(oc * 8 + ic) * 15 + tap]) : (unsigned short)0;
    } else if (idx < 4096 + 7680) {
        int j = idx - 4096;
        int t = j >> 9, rem = j & 511, oc = rem >> 5, ic = rem & 31;
        Wt2[j] = f2bf(rw2[(oc * 32 + ic) * 15 + t]);
    } else {
        int j = idx - 11776;   // < 4096
        int kb = j >> 9, rem = j & 511, m = rem >> 5, k = rem & 31;
        int tl = k >> 4, ic = k & 15, tap = kb * 2 + tl;
        Wt3[j] = (m < 8 && tap < 15) ? f2bf(rw3[(m * 16 + ic) * 15 + tap]) : (unsigned short)0;
    }
}

// ---------------- bf16 MFMA GEMM, global_load_lds staging -----------------
// A: M x 512 bf16 row-major. Bt: N x 512 bf16. 128x128 tile, BK=32.
// 1-D swizzled grid: nt=(bid>>3)&(NT-1), mt=(bid>>(3+L))*8+(bid&7) so the 4
// consecutive same-XCD blocks share one A-tile in that XCD's L2.
template<bool FUSE_GELU, bool OUT_BF16, int LOG2_NT>
__global__ __launch_bounds__(256) void gemm_lds_kernel(const unsigned short* __restrict__ A,
                                                       const unsigned short* __restrict__ Bt,
                                                       const float* __restrict__ bias,
                                                       void* __restrict__ Cout,
                                                       int out_stride, int n_valid) {
    __shared__ __align__(16) unsigned short As[128 * 32];
    __shared__ __align__(16) unsigned short Bs[128 * 32];
    const int tid  = threadIdx.x;
    const int lane = tid & 63;
    const int wid  = tid >> 6;
    const int bid  = blockIdx.x;
    const int nt   = (bid >> 3) & ((1 << LOG2_NT) - 1);
    const int mt   = (bid >> (3 + LOG2_NT)) * 8 + (bid & 7);
    const int m0 = mt * 128;
    const int n0 = nt * 128;
    const int mw = (wid >> 1) * 64;
    const int nw = (wid & 1) * 64;
    const int l15  = lane & 15;
    const int quad = lane >> 4;
    const int srow = lane >> 2;        // 0..15 within a 16-row chunk
    const int scol = (lane & 3) * 8;   // k-offset in shorts

    floatx4 acc[4][4];
#pragma unroll
    for (int i = 0; i < 4; ++i)
#pragma unroll
        for (int j = 0; j < 4; ++j) acc[i][j] = (floatx4)0.0f;

    for (int k0 = 0; k0 < 512; k0 += 32) {
        // async staging: wave w covers rows w*32 .. w*32+31 of both tiles
#pragma unroll
        for (int p = 0; p < 2; ++p) {
            const int rbase = wid * 32 + p * 16;
            async16(A  + (size_t)(m0 + rbase + srow) * 512 + k0 + scol, As + rbase * 32);
            async16(Bt + (size_t)(n0 + rbase + srow) * 512 + k0 + scol, Bs + rbase * 32);
        }
        __syncthreads();   // compiler drains vmcnt before barrier
        bf16x8 af[4], bfr[4];
#pragma unroll
        for (int t = 0; t < 4; ++t) {
            af[t]  = *(const bf16x8*)(As + (mw + t * 16 + l15) * 32 + quad * 8);
            bfr[t] = *(const bf16x8*)(Bs + (nw + t * 16 + l15) * 32 + quad * 8);
        }
#pragma unroll
        for (int mtl = 0; mtl < 4; ++mtl)
#pragma unroll
            for (int ntl = 0; ntl < 4; ++ntl)
                acc[mtl][ntl] = __builtin_amdgcn_mfma_f32_16x16x32_bf16(af[mtl], bfr[ntl], acc[mtl][ntl], 0, 0, 0);
        __syncthreads();
    }

#pragma unroll
    for (int mtl = 0; mtl < 4; ++mtl) {
#pragma unroll
        for (int ntl = 0; ntl < 4; ++ntl) {
            const int col  = n0 + nw + ntl * 16 + l15;
            const int rowb = m0 + mw + mtl * 16 + quad * 4;
            const bool colok = (col < n_valid);
            float bv = colok ? bias[col] : 0.0f;
#pragma unroll
            for (int r = 0; r < 4; ++r) {
                float v = acc[mtl][ntl][r] + bv;
                if (FUSE_GELU) v = gelu_erf(v);
                if (colok) {
                    size_t off = (size_t)(rowb + r) * out_stride + col;
                    if (OUT_BF16) ((unsigned short*)Cout)[off] = f2bf(v);
                    else          ((float*)Cout)[off] = v;
                }
            }
        }
    }
}

// ---------------- overlap-add (bf16 patches) -> rec pos-major fp32 --------
__global__ __launch_bounds__(256) void oadd_kernel(const unsigned short* __restrict__ patches,
                                                   float* __restrict__ rec) {
    int idx = blockIdx.x * 256 + threadIdx.x;   // exact 2,048,000
    int l = idx % OL;
    int b = idx / OL;
    int imin = (l >= PT) ? (l - (PT - PSTRIDE)) / PSTRIDE : 0;
    int imax = l / PSTRIDE; if (imax > NP - 1) imax = NP - 1;
    float acc[8];
#pragma unroll
    for (int c = 0; c < 8; ++c) acc[c] = 0.0f;
    float wsum = 0.0f;
    for (int i = imin; i <= imax; ++i) {
        int t = l - i * PSTRIDE;
        float w = (t < 50) ? t * (1.0f / 49.0f)
                           : ((t >= 150) ? (199 - t) * (1.0f / 49.0f) : 1.0f);
        wsum += w;
        const unsigned short* p = patches + ((size_t)(b * NP + i) * NC) * PT + t;
#pragma unroll
        for (int c = 0; c < 8; ++c) acc[c] += bf2f(p[c * PT]) * w;
    }
    float inv = 1.0f / fmaxf(wsum, 1e-8f);
    float4 v0 = { acc[0] * inv, acc[1] * inv, acc[2] * inv, acc[3] * inv };
    float4 v1 = { acc[4] * inv, acc[5] * inv, acc[6] * inv, acc[7] * inv };
    float* o = rec + (size_t)idx * 8;
    *(float4*)o = v0;
    *(float4*)(o + 4) = v1;
}

// ---------------- conv1 (8->32, k15) via MFMA -----------------------------
__global__ __launch_bounds__(256) void conv1_mfma(const float* __restrict__ rec,
                                                  const unsigned short* __restrict__ Wt1,
                                                  const float* __restrict__ rb1,
                                                  unsigned short* __restrict__ c1) {
    __shared__ __align__(16) unsigned short xs[272 * 8];    // [row][8ic], row=pos+7
    __shared__ __align__(16) unsigned short ys[256 * 40];   // [pos][32oc], stride 40
    __shared__ float bs[32];
    const int tid = threadIdx.x;
    const int b = blockIdx.y;
    const int seg0 = blockIdx.x * 256;
    const int lane = tid & 63, wid = tid >> 6;
    const int l15 = lane & 15, quad = lane >> 4;

    if (tid < 32) bs[tid] = rb1[tid];
    for (int i = tid; i < 544; i += 256) {
        int row = i >> 1, half = i & 1;
        int p = seg0 - 7 + row;
        float4 v = (p >= 0 && p < OL) ? *(const float4*)(rec + ((size_t)b * OL + p) * 8 + half * 4)
                                      : make_float4(0.f, 0.f, 0.f, 0.f);
        ushort4 o; o.x = f2bf(v.x); o.y = f2bf(v.y); o.z = f2bf(v.z); o.w = f2bf(v.w);
        *(ushort4*)(xs + row * 8 + half * 4) = o;
    }
    bf16x8 wfrag[4][2];
#pragma unroll
    for (int kb = 0; kb < 4; ++kb)
#pragma unroll
        for (int ot = 0; ot < 2; ++ot)
            wfrag[kb][ot] = *(const bf16x8*)(Wt1 + (kb * 32 + ot * 16 + l15) * 32 + quad * 8);
    __syncthreads();

    floatx4 acc[2][4];
#pragma unroll
    for (int ot = 0; ot < 2; ++ot)
#pragma unroll
        for (int u = 0; u < 4; ++u) acc[ot][u] = (floatx4)0.0f;

#pragma unroll
    for (int u = 0; u < 4; ++u) {
        const int posl = wid * 64 + u * 16 + l15;
#pragma unroll
        for (int kb = 0; kb < 4; ++kb) {
            int row = posl + kb * 4 + quad;
            bf16x8 bfrag = *(const bf16x8*)(xs + row * 8);
#pragma unroll
            for (int ot = 0; ot < 2; ++ot)
                acc[ot][u] = __builtin_amdgcn_mfma_f32_16x16x32_bf16(wfrag[kb][ot], bfrag, acc[ot][u], 0, 0, 0);
        }
    }
#pragma unroll
    for (int ot = 0; ot < 2; ++ot)
#pragma unroll
        for (int u = 0; u < 4; ++u) {
            int posl = wid * 64 + u * 16 + l15;
            int oc0 = ot * 16 + quad * 4;
            ushort4 o;
            o.x = f2bf(gelu_erf(acc[ot][u][0] + bs[oc0]));
            o.y = f2bf(gelu_erf(acc[ot][u][1] + bs[oc0 + 1]));
            o.z = f2bf(gelu_erf(acc[ot][u][2] + bs[oc0 + 2]));
            o.w = f2bf(gelu_erf(acc[ot][u][3] + bs[oc0 + 3]));
            *(ushort4*)(ys + posl * 40 + oc0) = o;   // one ds_write_b64
        }
    __syncthreads();
    for (int i = tid; i < 1024; i += 256) {
        int row = i >> 2, ch = i & 3;
        int p = seg0 + row;
        if (p < OL)
            *(int4*)(c1 + ((size_t)b * OL + p) * 32 + ch * 8) = *(const int4*)(ys + row * 40 + ch * 8);
    }
}

// ---------------- conv2 (32->16, k15) via MFMA ----------------------------
__global__ __launch_bounds__(256) void conv2_mfma(const unsigned short* __restrict__ c1,
                                                  const unsigned short* __restrict__ Wt2,
                                                  const float* __restrict__ rb2,
                                                  unsigned short* __restrict__ c2) {
    __shared__ __align__(16) unsigned short xs[270 * 40];
    __shared__ __align__(16) unsigned short ys[256 * 24];
    __shared__ float bs[16];
    const int tid = threadIdx.x;
    const int b = blockIdx.y;
    const int seg0 = blockIdx.x * 256;
    const int lane = tid & 63, wid = tid >> 6;
    const int l15 = lane & 15, quad = lane >> 4;

    if (tid < 16) bs[tid] = rb2[tid];
    for (int i = tid; i < 1080; i += 256) {
        int row = i >> 2, ch = i & 3;
        int p = seg0 - 7 + row;
        int4 v = (p >= 0 && p < OL) ? *(const int4*)(c1 + ((size_t)b * OL + p) * 32 + ch * 8)
                                    : make_int4(0, 0, 0, 0);
        *(int4*)(xs + row * 40 + ch * 8) = v;
    }
    bf16x8 wfrag[15];
#pragma unroll
    for (int t = 0; t < 15; ++t)
        wfrag[t] = *(const bf16x8*)(Wt2 + (t * 16 + l15) * 32 + quad * 8);
    __syncthreads();

    floatx4 acc[4];
#pragma unroll
    for (int u = 0; u < 4; ++u) acc[u] = (floatx4)0.0f;

#pragma unroll
    for (int u = 0; u < 4; ++u) {
        const int posl = wid * 64 + u * 16 + l15;
#pragma unroll
        for (int t = 0; t < 15; ++t) {
            bf16x8 bfrag = *(const bf16x8*)(xs + (posl + t) * 40 + quad * 8);
            acc[u] = __builtin_amdgcn_mfma_f32_16x16x32_bf16(wfrag[t], bfrag, acc[u], 0, 0, 0);
        }
    }
#pragma unroll
    for (int u = 0; u < 4; ++u) {
        int posl = wid * 64 + u * 16 + l15;
        int oc0 = quad * 4;
        ushort4 o;
        o.x = f2bf(gelu_erf(acc[u][0] + bs[oc0]));
        o.y = f2bf(gelu_erf(acc[u][1] + bs[oc0 + 1]));
        o.z = f2bf(gelu_erf(acc[u][2] + bs[oc0 + 2]));
        o.w = f2bf(gelu_erf(acc[u][3] + bs[oc0 + 3]));
        *(ushort4*)(ys + posl * 24 + oc0) = o;
    }
    __syncthreads();
    for (int i = tid; i < 512; i += 256) {
        int row = i >> 1, ch = i & 1;
        int p = seg0 + row;
        if (p < OL)
            *(int4*)(c2 + ((size_t)b * OL + p) * 16 + ch * 8) = *(const int4*)(ys + row * 24 + ch * 8);
    }
}

// ---------------- conv3 (16->8) + residual + pointwise -> out -------------
__global__ __launch_bounds__(256) void conv3pw_mfma(const unsigned short* __restrict__ c2,
                                                    const float* __restrict__ rec,
                                                    const unsigned short* __restrict__ Wt3,
                                                    const float* __restrict__ rb3,
                                                    const float* __restrict__ pw,
                                                    const float* __restrict__ pb,
                                                    float* __restrict__ out) {
    __shared__ __align__(16) unsigned short xs[272 * 24];
    __shared__ __align__(16) float r2[256 * 12];
    __shared__ float pws[64], bs3[8], bsp[8];
    const int tid = threadIdx.x;
    const int b = blockIdx.y;
    const int seg0 = blockIdx.x * 256;
    const int lane = tid & 63, wid = tid >> 6;
    const int l15 = lane & 15, quad = lane >> 4;

    if (tid < 64) pws[tid] = pw[tid];
    if (tid >= 64 && tid < 72) bs3[tid - 64] = rb3[tid - 64];
    if (tid >= 72 && tid < 80) bsp[tid - 72] = pb[tid - 72];
    for (int i = tid; i < 544; i += 256) {
        int row = i >> 1, ch = i & 1;
        int p = seg0 - 7 + row;
        int4 v = (p >= 0 && p < OL) ? *(const int4*)(c2 + ((size_t)b * OL + p) * 16 + ch * 8)
                                    : make_int4(0, 0, 0, 0);
        *(int4*)(xs + row * 24 + ch * 8) = v;
    }
    for (int i = tid; i < 512; i += 256) {
        int row = i >> 1, half = i & 1;
        int p = seg0 + row;
        float4 v = (p < OL) ? *(const float4*)(rec + ((size_t)b * OL + p) * 8 + half * 4)
                            : make_float4(0.f, 0.f, 0.f, 0.f);
        *(float4*)(r2 + row * 12 + half * 4) = v;
    }
    bf16x8 wfrag[8];
#pragma unroll
    for (int kb = 0; kb < 8; ++kb)
        wfrag[kb] = *(const bf16x8*)(Wt3 + (kb * 16 + l15) * 32 + quad * 8);
    __syncthreads();

    floatx4 acc[4];
#pragma unroll
    for (int u = 0; u < 4; ++u) acc[u] = (floatx4)0.0f;

#pragma unroll
    for (int u = 0; u < 4; ++u) {
        const int posl = wid * 64 + u * 16 + l15;
#pragma unroll
        for (int kb = 0; kb < 8; ++kb) {
            int row = posl + kb * 2 + (quad >> 1);
            bf16x8 bfrag = *(const bf16x8*)(xs + row * 24 + (quad & 1) * 8);
            acc[u] = __builtin_amdgcn_mfma_f32_16x16x32_bf16(wfrag[kb], bfrag, acc[u], 0, 0, 0);
        }
    }
    if (quad < 2) {
#pragma unroll
        for (int u = 0; u < 4; ++u) {
            int posl = wid * 64 + u * 16 + l15;
            int oc0 = quad * 4;
            float4 rv = *(const float4*)(r2 + posl * 12 + oc0);
            rv.x += acc[u][0] + bs3[oc0];
            rv.y += acc[u][1] + bs3[oc0 + 1];
            rv.z += acc[u][2] + bs3[oc0 + 2];
            rv.w += acc[u][3] + bs3[oc0 + 3];
            *(float4*)(r2 + posl * 12 + oc0) = rv;
        }
    }
    __syncthreads();
    {
        int p = seg0 + tid;
        if (p < OL) {
            float4 a = *(const float4*)(r2 + tid * 12);
            float4 c = *(const float4*)(r2 + tid * 12 + 4);
#pragma unroll
            for (int o = 0; o < 8; ++o) {
                float v = bsp[o];
                v += pws[o * 8 + 0] * a.x + pws[o * 8 + 1] * a.y + pws[o * 8 + 2] * a.z + pws[o * 8 + 3] * a.w;
                v += pws[o * 8 + 4] * c.x + pws[o * 8 + 5] * c.y + pws[o * 8 + 6] * c.z + pws[o * 8 + 7] * c.w;
                out[((size_t)b * 8 + o) * OL + p] = v;
            }
        }
    }
}

// ---------------------------------------------------------------------------
extern "C" void kernel_launch(void* const* d_in, const int* in_sizes, int n_in,
                              void* d_out, int out_size, void* d_ws, size_t ws_size,
                              hipStream_t stream) {
    const float* X   = (const float*)d_in[0];
    const float* W1  = (const float*)d_in[1];
    const float* b1  = (const float*)d_in[2];
    const float* W2  = (const float*)d_in[3];
    const float* b2  = (const float*)d_in[4];
    const float* rw1 = (const float*)d_in[5];
    const float* rb1 = (const float*)d_in[6];
    const float* rw2 = (const float*)d_in[7];
    const float* rb2 = (const float*)d_in[8];
    const float* rw3 = (const float*)d_in[9];
    const float* rb3 = (const float*)d_in[10];
    const float* pw  = (const float*)d_in[11];
    const float* pb  = (const float*)d_in[12];
    float* out = (float*)d_out;

    char* ws = (char*)d_ws;
    unsigned short* Xb  = (unsigned short*)(ws);               //  92,274,688
    unsigned short* W1t = (unsigned short*)(ws +  92274688);   //     524,288
    unsigned short* W2t = (unsigned short*)(ws +  92798976);   //     262,144
    unsigned short* h   = (unsigned short*)(ws +  93061120);   //  92,274,688
    unsigned short* pat = (unsigned short*)(ws + 185335808);   //  36,044,800 (bf16 patches)
    float*          rec = (float*)         (ws + 257425408);   //  65,536,000 (pos-major)
    unsigned short* Wt1 = (unsigned short*)(ws + 322961408);   //       8,192
    unsigned short* Wt2 = (unsigned short*)(ws + 322969600);   //      15,360
    unsigned short* Wt3 = (unsigned short*)(ws + 322984960);   //       8,192 -> 322,993,152 total
    unsigned short* c1  = (unsigned short*)(ws);               // 131,072,000 (over dead Xb/W1t/W2t/h-head)
    unsigned short* c2  = (unsigned short*)(ws + 131072000);   //  65,536,000 (over dead h-tail/pat-head)

    cast_x_kernel<<<45056, 256, 0, stream>>>(X, Xb);
    prep_w_kernel<<<1536, 256, 0, stream>>>(W1, W2, W1t, W2t);
    prep_cw_kernel<<<62, 256, 0, stream>>>(rw1, rw2, rw3, Wt1, Wt2, Wt3);
    gemm_lds_kernel<true,  true, 2><<<2816, 256, 0, stream>>>(Xb, W1t, b1, (void*)h,   512, 512);
    gemm_lds_kernel<false, true, 1><<<1408, 256, 0, stream>>>(h,  W2t, b2, (void*)pat, 200, 200);
    oadd_kernel<<<8000, 256, 0, stream>>>(pat, rec);
    conv1_mfma<<<dim3(8, NB), 256, 0, stream>>>(rec, Wt1, rb1, c1);
    conv2_mfma<<<dim3(8, NB), 256, 0, stream>>>(c1, Wt2, rb2, c2);
    conv3pw_mfma<<<dim3(8, NB), 256, 0, stream>>>(c2, rec, Wt3, rb3, pw, pb, out);
}